// Round 1
// baseline (1259.446 us; speedup 1.0000x reference)
//
#include <hip/hip_runtime.h>
#include <math.h>

// MultiScaleTransformerGSM on MI355X (gfx950).
// Pipeline: LN+ReLU -> (per branch) depthwise conv over T -> gate GEMM
// (bf16 MFMA) w/ sigmoid*x + shifted scatter-accumulate -> convert ->
// proj1 GEMM + gelu -> proj2 GEMM + residual.

#define MROWS 25216   // B*T*N = 8*16*197
#define CD    768
#define NTOK  197
#define TFR   16

typedef __attribute__((ext_vector_type(8))) short short8;
typedef __attribute__((ext_vector_type(4))) float floatx4;

__device__ __forceinline__ unsigned short f2bf(float f) {
    union { float f; unsigned u; } v; v.f = f;
    unsigned r = v.u + 0x7FFFu + ((v.u >> 16) & 1u);
    return (unsigned short)(r >> 16);
}
__device__ __forceinline__ float bf2f(unsigned short h) {
    union { unsigned u; float f; } v; v.u = ((unsigned)h) << 16;
    return v.f;
}

// ---------------- LayerNorm + ReLU -> bf16 ----------------
__global__ __launch_bounds__(256)
void ln_relu_kernel(const float* __restrict__ x, const float* __restrict__ g,
                    const float* __restrict__ b, unsigned short* __restrict__ xn) {
    int row = blockIdx.x;
    int tid = threadIdx.x;
    const float* xr = x + (size_t)row * CD;
    float v0 = xr[tid], v1 = xr[tid + 256], v2 = xr[tid + 512];
    float s = v0 + v1 + v2;
    __shared__ float red[8];
#pragma unroll
    for (int off = 32; off; off >>= 1) s += __shfl_down(s, off, 64);
    int lane = tid & 63, w = tid >> 6;
    if (lane == 0) red[w] = s;
    __syncthreads();
    float mean = (red[0] + red[1] + red[2] + red[3]) * (1.0f / CD);
    float d0 = v0 - mean, d1 = v1 - mean, d2 = v2 - mean;
    float s2 = d0 * d0 + d1 * d1 + d2 * d2;
#pragma unroll
    for (int off = 32; off; off >>= 1) s2 += __shfl_down(s2, off, 64);
    if (lane == 0) red[4 + w] = s2;
    __syncthreads();
    float var = (red[4] + red[5] + red[6] + red[7]) * (1.0f / CD);
    float inv = rsqrtf(var + 1e-5f);
    unsigned short* xo = xn + (size_t)row * CD;
    float o0 = fmaxf(d0 * inv * g[tid]       + b[tid],       0.0f);
    float o1 = fmaxf(d1 * inv * g[tid + 256] + b[tid + 256], 0.0f);
    float o2 = fmaxf(d2 * inv * g[tid + 512] + b[tid + 512], 0.0f);
    xo[tid] = f2bf(o0); xo[tid + 256] = f2bf(o1); xo[tid + 512] = f2bf(o2);
}

// ---------------- Depthwise conv over T (per branch) ----------------
__global__ __launch_bounds__(256)
void dwconv_kernel(const unsigned short* __restrict__ xn, const float* __restrict__ cw,
                   const float* __restrict__ cb, unsigned short* __restrict__ feat,
                   int d) {
    int gid = blockIdx.x * 256 + threadIdx.x;     // 25216*96 threads, 8 ch each
    int r  = gid / 96;
    int cg = gid - r * 96;
    int c0 = cg * 8;
    int t  = (r / NTOK) & 15;
    int kk = 2 * d + 1;
    float acc[8];
#pragma unroll
    for (int q = 0; q < 8; ++q) acc[q] = cb[c0 + q];
    for (int j = 0; j < kk; ++j) {
        int tj = t + j - d;
        if (tj < 0 || tj >= TFR) continue;
        const unsigned short* p = xn + ((size_t)r + (size_t)(j - d) * NTOK) * CD + c0;
        short8 u = *(const short8*)p;
#pragma unroll
        for (int q = 0; q < 8; ++q)
            acc[q] += bf2f((unsigned short)u[q]) * cw[(c0 + q) * kk + j];
    }
    short8 o;
#pragma unroll
    for (int q = 0; q < 8; ++q) o[q] = (short)f2bf(acc[q]);
    *(short8*)(feat + (size_t)r * CD + c0) = o;
}

// ---------------- weight transpose+convert: wt[n][k] = bf16(w[k][n]) ----------------
__global__ __launch_bounds__(256)
void wprep_kernel(const float* __restrict__ w, unsigned short* __restrict__ wt) {
    int gid = blockIdx.x * 256 + threadIdx.x;     // 768*768
    int n = gid / CD, k = gid - n * CD;
    wt[gid] = f2bf(w[(size_t)k * CD + n]);
}

// ---------------- fp32 -> bf16 convert ----------------
__global__ __launch_bounds__(256)
void f2b_kernel(const float* __restrict__ in, unsigned short* __restrict__ out) {
    int gid = blockIdx.x * 256 + threadIdx.x;     // n/4 threads
    floatx4 v = *(const floatx4*)(in + (size_t)gid * 4);
    union { unsigned short s[4]; unsigned long long ll; } o;
#pragma unroll
    for (int q = 0; q < 4; ++q) o.s[q] = f2bf(v[q]);
    *(unsigned long long*)(out + (size_t)gid * 4) = o.ll;
}

// ---------------- 128x128-tile bf16 MFMA GEMM with fused epilogues ----------------
// EPI 0: gate  -> sigmoid(acc+bias)*x, scatter += wd*y into outf with time shift
// EPI 1: proj1 -> gelu(acc+bias) -> bf16 outh
// EPI 2: proj2 -> acc+bias+x -> fp32 outf
template <int EPI>
__global__ __launch_bounds__(256)
void gemm_kernel(const unsigned short* __restrict__ A,    // M x 768, bf16
                 const unsigned short* __restrict__ Bt,   // 768 x 768 bf16, N-major
                 const float* __restrict__ bias,
                 const float* __restrict__ xaux,
                 float* __restrict__ outf,
                 unsigned short* __restrict__ outh,
                 const float* __restrict__ fw,
                 int dshift) {
    __shared__ unsigned short As[128][40];   // +8 pad: keeps 16B align, ~2-way banks (free)
    __shared__ unsigned short Bs[128][40];
    int tid  = threadIdx.x;
    int n0   = blockIdx.x * 128;
    int m0   = blockIdx.y * 128;
    int wave = tid >> 6, lane = tid & 63;
    int wm   = (wave >> 1) * 64, wn = (wave & 1) * 64;
    int quad = lane >> 4, l16 = lane & 15;

    floatx4 acc[4][4];
#pragma unroll
    for (int i = 0; i < 4; ++i)
#pragma unroll
        for (int j = 0; j < 4; ++j) acc[i][j] = (floatx4){0.f, 0.f, 0.f, 0.f};

    int sr = tid >> 2;            // 0..63 staging row
    int sk = (tid & 3) * 8;       // 0,8,16,24 staging k-chunk

    for (int kt = 0; kt < CD; kt += 32) {
        __syncthreads();
#pragma unroll
        for (int h = 0; h < 2; ++h) {
            int row = sr + h * 64;
            *(short8*)(&As[row][sk]) = *(const short8*)(A  + (size_t)(m0 + row) * CD + kt + sk);
            *(short8*)(&Bs[row][sk]) = *(const short8*)(Bt + (size_t)(n0 + row) * CD + kt + sk);
        }
        __syncthreads();
        short8 af[4], bfr[4];
#pragma unroll
        for (int i = 0; i < 4; ++i) af[i]  = *(const short8*)(&As[wm + i * 16 + l16][quad * 8]);
#pragma unroll
        for (int j = 0; j < 4; ++j) bfr[j] = *(const short8*)(&Bs[wn + j * 16 + l16][quad * 8]);
#pragma unroll
        for (int i = 0; i < 4; ++i)
#pragma unroll
            for (int j = 0; j < 4; ++j)
                acc[i][j] = __builtin_amdgcn_mfma_f32_16x16x32_bf16(af[i], bfr[j], acc[i][j], 0, 0, 0);
    }

    float wd = 0.f;
    if (EPI == 0) {
        float f0 = fw[0], f1 = fw[1], f2 = fw[2];
        float mx = fmaxf(f0, fmaxf(f1, f2));
        float e0 = expf(f0 - mx), e1 = expf(f1 - mx), e2 = expf(f2 - mx);
        float inv = 1.f / (e0 + e1 + e2);
        wd = (dshift == 1 ? e0 : dshift == 2 ? e1 : e2) * inv;
    }

#pragma unroll
    for (int j = 0; j < 4; ++j) {
        int col = n0 + wn + j * 16 + l16;
        float bc = bias[col];
#pragma unroll
        for (int i = 0; i < 4; ++i) {
#pragma unroll
            for (int r = 0; r < 4; ++r) {
                int row = m0 + wm + i * 16 + quad * 4 + r;   // C/D: col=lane&15, row=quad*4+reg
                float v = acc[i][j][r] + bc;
                if (EPI == 0) {
                    float gte = 1.f / (1.f + expf(-v));
                    float y = gte * xaux[(size_t)row * CD + col];
                    int t = (row / NTOK) & 15;
                    int mp = row; bool ok = true;
                    if (col < 256)      { mp = row - dshift * NTOK; ok = (t >= dshift); }
                    else if (col < 512) { mp = row + dshift * NTOK; ok = (t + dshift < TFR); }
                    if (ok) outf[(size_t)mp * CD + col] += wd * y;   // injective per branch
                } else if (EPI == 1) {
                    float gl = 0.5f * v * (1.0f + erff(v * 0.70710678118f));
                    outh[(size_t)row * CD + col] = f2bf(gl);
                } else {
                    outf[(size_t)row * CD + col] = v + xaux[(size_t)row * CD + col];
                }
            }
        }
    }
}

extern "C" void kernel_launch(void* const* d_in, const int* in_sizes, int n_in,
                              void* d_out, int out_size, void* d_ws, size_t ws_size,
                              hipStream_t stream) {
    const float* x      = (const float*)d_in[0];
    const float* ln_g   = (const float*)d_in[1];
    const float* ln_b   = (const float*)d_in[2];
    const float* gate_w = (const float*)d_in[3];
    const float* gate_b = (const float*)d_in[4];
    const float* pw1    = (const float*)d_in[5];
    const float* pb1    = (const float*)d_in[6];
    const float* pw2    = (const float*)d_in[7];
    const float* pb2    = (const float*)d_in[8];
    const float* fw     = (const float*)d_in[9];
    // d_in[10] = num_frames (16, hardcoded)
    const float* cw[3]  = {(const float*)d_in[11], (const float*)d_in[13], (const float*)d_in[15]};
    const float* cb[3]  = {(const float*)d_in[12], (const float*)d_in[14], (const float*)d_in[16]};

    char* ws = (char*)d_ws;
    unsigned short* gwt  = (unsigned short*)(ws + 0);           // 768*768*2
    unsigned short* p1t  = (unsigned short*)(ws + 1179648);
    unsigned short* p2t  = (unsigned short*)(ws + 2359296);
    unsigned short* xn   = (unsigned short*)(ws + 3538944);     // 25216*768*2
    unsigned short* feat = (unsigned short*)(ws + 42270720);    // 25216*768*2 (reused per branch)
    float*          fused= (float*)         (ws + 81002496);    // 25216*768*4
    unsigned short* fsb  = (unsigned short*)(ws + 158466048);   // 25216*768*2
    unsigned short* h1   = (unsigned short*)(ws + 197197824);   // 25216*768*2
    // total ws use: 235929600 bytes

    wprep_kernel<<<2304, 256, 0, stream>>>(gate_w, gwt);
    wprep_kernel<<<2304, 256, 0, stream>>>(pw1, p1t);
    wprep_kernel<<<2304, 256, 0, stream>>>(pw2, p2t);
    ln_relu_kernel<<<MROWS, 256, 0, stream>>>(x, ln_g, ln_b, xn);
    hipMemsetAsync(fused, 0, (size_t)MROWS * CD * 4, stream);

    dim3 gg(6, 197);   // 768/128 cols x 25216/128 rows
    for (int i = 0; i < 3; ++i) {
        dwconv_kernel<<<9456, 256, 0, stream>>>(xn, cw[i], cb[i], feat, i + 1);
        gemm_kernel<0><<<gg, 256, 0, stream>>>(feat, gwt, gate_b, x, fused, nullptr, fw, i + 1);
    }
    f2b_kernel<<<18912, 256, 0, stream>>>(fused, fsb);
    gemm_kernel<1><<<gg, 256, 0, stream>>>(fsb, p1t, pb1, nullptr, nullptr, h1, nullptr, 0);
    gemm_kernel<2><<<gg, 256, 0, stream>>>(h1, p2t, pb2, x, (float*)d_out, nullptr, nullptr, 0);
}

// Round 2
// 980.660 us; speedup vs baseline: 1.2843x; 1.2843x over previous
//
#include <hip/hip_runtime.h>
#include <math.h>

// MultiScaleTransformerGSM on MI355X (gfx950).
// LN+ReLU -> (per branch) T-register-blocked depthwise conv -> gate GEMM
// (bf16 MFMA) w/ sigmoid*x + shifted scatter (branch1: pure write+zero-fill,
// branch3: fused fp32->bf16 emit) -> proj1 GEMM + gelu -> proj2 GEMM + residual.

#define MROWS 25216   // B*T*N = 8*16*197
#define CD    768
#define NTOK  197
#define TFR   16
#define NB    8

typedef __attribute__((ext_vector_type(8))) short short8;
typedef __attribute__((ext_vector_type(4))) float floatx4;

__device__ __forceinline__ unsigned short f2bf(float f) {
    union { float f; unsigned u; } v; v.f = f;
    unsigned r = v.u + 0x7FFFu + ((v.u >> 16) & 1u);
    return (unsigned short)(r >> 16);
}
__device__ __forceinline__ float bf2f(unsigned short h) {
    union { unsigned u; float f; } v; v.u = ((unsigned)h) << 16;
    return v.f;
}

// ---------------- LayerNorm + ReLU -> bf16 ----------------
__global__ __launch_bounds__(256)
void ln_relu_kernel(const float* __restrict__ x, const float* __restrict__ g,
                    const float* __restrict__ b, unsigned short* __restrict__ xn) {
    int row = blockIdx.x;
    int tid = threadIdx.x;
    const float* xr = x + (size_t)row * CD;
    float v0 = xr[tid], v1 = xr[tid + 256], v2 = xr[tid + 512];
    float s = v0 + v1 + v2;
    __shared__ float red[8];
#pragma unroll
    for (int off = 32; off; off >>= 1) s += __shfl_down(s, off, 64);
    int lane = tid & 63, w = tid >> 6;
    if (lane == 0) red[w] = s;
    __syncthreads();
    float mean = (red[0] + red[1] + red[2] + red[3]) * (1.0f / CD);
    float d0 = v0 - mean, d1 = v1 - mean, d2 = v2 - mean;
    float s2 = d0 * d0 + d1 * d1 + d2 * d2;
#pragma unroll
    for (int off = 32; off; off >>= 1) s2 += __shfl_down(s2, off, 64);
    if (lane == 0) red[4 + w] = s2;
    __syncthreads();
    float var = (red[4] + red[5] + red[6] + red[7]) * (1.0f / CD);
    float inv = rsqrtf(var + 1e-5f);
    unsigned short* xo = xn + (size_t)row * CD;
    float o0 = fmaxf(d0 * inv * g[tid]       + b[tid],       0.0f);
    float o1 = fmaxf(d1 * inv * g[tid + 256] + b[tid + 256], 0.0f);
    float o2 = fmaxf(d2 * inv * g[tid + 512] + b[tid + 512], 0.0f);
    xo[tid] = f2bf(o0); xo[tid + 256] = f2bf(o1); xo[tid + 512] = f2bf(o2);
}

// ---------------- Depthwise conv over T, full-T register blocking ----------------
// One thread: one (b,n) token, 8 channels, ALL 16 frames in registers.
// 16 independent loads (ILP), each xn byte read exactly once, fully unrolled.
template <int D>
__global__ __launch_bounds__(256)
void dwconv_kernel(const unsigned short* __restrict__ xn, const float* __restrict__ cw,
                   const float* __restrict__ cb, unsigned short* __restrict__ feat) {
    constexpr int KK = 2 * D + 1;
    int gid = blockIdx.x * 256 + threadIdx.x;     // 8*197*96 = 151296 = 591*256 exact
    int bn = gid / 96;                            // 0..1575 = b*197+n
    int cg = gid - bn * 96;
    int c0 = cg * 8;
    size_t base = (size_t)bn % NTOK;              // n
    int b = bn / NTOK;
    base = ((size_t)b * TFR * NTOK + (bn - b * NTOK)) * CD + c0;
    const size_t tstride = (size_t)NTOK * CD;

    short8 u[TFR];
#pragma unroll
    for (int t = 0; t < TFR; ++t)
        u[t] = *(const short8*)(xn + base + (size_t)t * tstride);

    float wgt[8][KK], bb[8];
#pragma unroll
    for (int q = 0; q < 8; ++q) {
        bb[q] = cb[c0 + q];
#pragma unroll
        for (int j = 0; j < KK; ++j) wgt[q][j] = cw[(c0 + q) * KK + j];
    }

#pragma unroll
    for (int t = 0; t < TFR; ++t) {
        float acc[8];
#pragma unroll
        for (int q = 0; q < 8; ++q) acc[q] = bb[q];
#pragma unroll
        for (int j = 0; j < KK; ++j) {
            constexpr int DD = D;
            int tj = t + j - DD;
            if (tj < 0 || tj >= TFR) continue;   // compile-time resolved (t,j unrolled)
#pragma unroll
            for (int q = 0; q < 8; ++q)
                acc[q] += bf2f((unsigned short)u[tj][q]) * wgt[q][j];
        }
        short8 o;
#pragma unroll
        for (int q = 0; q < 8; ++q) o[q] = (short)f2bf(acc[q]);
        *(short8*)(feat + base + (size_t)t * tstride) = o;
    }
}

// ---------------- weight transpose+convert: wt[n][k] = bf16(w[k][n]) ----------------
__global__ __launch_bounds__(256)
void wprep3_kernel(const float* __restrict__ w0, const float* __restrict__ w1,
                   const float* __restrict__ w2, unsigned short* __restrict__ t0,
                   unsigned short* __restrict__ t1, unsigned short* __restrict__ t2) {
    const float* w = blockIdx.y == 0 ? w0 : blockIdx.y == 1 ? w1 : w2;
    unsigned short* wt = blockIdx.y == 0 ? t0 : blockIdx.y == 1 ? t1 : t2;
    int gid = blockIdx.x * 256 + threadIdx.x;     // 768*768
    int n = gid / CD, k = gid - n * CD;
    wt[gid] = f2bf(w[(size_t)k * CD + n]);
}

// ---------------- 128x128-tile bf16 MFMA GEMM with fused epilogues ----------------
// EPI 0: gate d=1 first branch  -> pure write of wd*y (shifted) + zero-fill
// EPI 1: gate d=2 mid           -> accumulate wd*y (shifted)
// EPI 2: gate d=3 last          -> accumulate + emit bf16 fsb (incl. complement fill)
// EPI 3: proj1 -> gelu(acc+bias) -> bf16 outh
// EPI 4: proj2 -> acc+bias+x -> fp32 outf
template <int EPI>
__global__ __launch_bounds__(256)
void gemm_kernel(const unsigned short* __restrict__ A,    // M x 768, bf16
                 const unsigned short* __restrict__ Bt,   // 768 x 768 bf16, N-major
                 const float* __restrict__ bias,
                 const float* __restrict__ xaux,
                 float* __restrict__ outf,
                 unsigned short* __restrict__ outh,
                 const float* __restrict__ fw) {
    __shared__ unsigned short As[128][40];
    __shared__ unsigned short Bs[128][40];
    int tid  = threadIdx.x;
    int n0   = blockIdx.x * 128;
    int m0   = blockIdx.y * 128;
    int wave = tid >> 6, lane = tid & 63;
    int wm   = (wave >> 1) * 64, wn = (wave & 1) * 64;
    int quad = lane >> 4, l16 = lane & 15;

    floatx4 acc[4][4];
#pragma unroll
    for (int i = 0; i < 4; ++i)
#pragma unroll
        for (int j = 0; j < 4; ++j) acc[i][j] = (floatx4){0.f, 0.f, 0.f, 0.f};

    int sr = tid >> 2;
    int sk = (tid & 3) * 8;

    for (int kt = 0; kt < CD; kt += 32) {
        __syncthreads();
#pragma unroll
        for (int h = 0; h < 2; ++h) {
            int row = sr + h * 64;
            *(short8*)(&As[row][sk]) = *(const short8*)(A  + (size_t)(m0 + row) * CD + kt + sk);
            *(short8*)(&Bs[row][sk]) = *(const short8*)(Bt + (size_t)(n0 + row) * CD + kt + sk);
        }
        __syncthreads();
        short8 af[4], bfr[4];
#pragma unroll
        for (int i = 0; i < 4; ++i) af[i]  = *(const short8*)(&As[wm + i * 16 + l16][quad * 8]);
#pragma unroll
        for (int j = 0; j < 4; ++j) bfr[j] = *(const short8*)(&Bs[wn + j * 16 + l16][quad * 8]);
#pragma unroll
        for (int i = 0; i < 4; ++i)
#pragma unroll
            for (int j = 0; j < 4; ++j)
                acc[i][j] = __builtin_amdgcn_mfma_f32_16x16x32_bf16(af[i], bfr[j], acc[i][j], 0, 0, 0);
    }

    constexpr int DSH = (EPI == 0) ? 1 : (EPI == 1) ? 2 : 3;
    float wd = 0.f;
    if (EPI <= 2) {
        float f0 = fw[0], f1 = fw[1], f2 = fw[2];
        float mx = fmaxf(f0, fmaxf(f1, f2));
        float e0 = expf(f0 - mx), e1 = expf(f1 - mx), e2 = expf(f2 - mx);
        float inv = 1.f / (e0 + e1 + e2);
        wd = (EPI == 0 ? e0 : EPI == 1 ? e1 : e2) * inv;
    }

#pragma unroll
    for (int j = 0; j < 4; ++j) {
        int col = n0 + wn + j * 16 + l16;
        float bc = bias[col];
#pragma unroll
        for (int i = 0; i < 4; ++i) {
#pragma unroll
            for (int r = 0; r < 4; ++r) {
                int row = m0 + wm + i * 16 + quad * 4 + r;
                float v = acc[i][j][r] + bc;
                if (EPI <= 2) {
                    float gte = 1.f / (1.f + expf(-v));
                    float contrib = wd * gte * xaux[(size_t)row * CD + col];
                    int t = (row / NTOK) & 15;
                    if (EPI == 0) {
                        // pure write + zero-fill (covers every target exactly once)
                        if (col < 256) {
                            if (t >= 1) outf[(size_t)(row - NTOK) * CD + col] = contrib;
                            else        outf[(size_t)(row + 15 * NTOK) * CD + col] = 0.f;
                        } else if (col < 512) {
                            if (t <= 14) outf[(size_t)(row + NTOK) * CD + col] = contrib;
                            else         outf[(size_t)(row - 15 * NTOK) * CD + col] = 0.f;
                        } else {
                            outf[(size_t)row * CD + col] = contrib;
                        }
                    } else if (EPI == 1) {
                        int mp = row; bool ok = true;
                        if (col < 256)      { mp = row - DSH * NTOK; ok = (t >= DSH); }
                        else if (col < 512) { mp = row + DSH * NTOK; ok = (t + DSH < TFR); }
                        if (ok) outf[(size_t)mp * CD + col] += contrib;
                    } else { // EPI == 2: accumulate + emit bf16
                        if (col < 256) {
                            if (t >= 3) {
                                size_t idx = (size_t)(row - 3 * NTOK) * CD + col;
                                float nv = outf[idx] + contrib;
                                outf[idx] = nv; outh[idx] = f2bf(nv);
                            } else {  // complement target t+13 (never written by branch 3)
                                size_t idx = (size_t)(row + 13 * NTOK) * CD + col;
                                outh[idx] = f2bf(outf[idx]);
                            }
                        } else if (col < 512) {
                            if (t <= 12) {
                                size_t idx = (size_t)(row + 3 * NTOK) * CD + col;
                                float nv = outf[idx] + contrib;
                                outf[idx] = nv; outh[idx] = f2bf(nv);
                            } else {
                                size_t idx = (size_t)(row - 13 * NTOK) * CD + col;
                                outh[idx] = f2bf(outf[idx]);
                            }
                        } else {
                            size_t idx = (size_t)row * CD + col;
                            float nv = outf[idx] + contrib;
                            outf[idx] = nv; outh[idx] = f2bf(nv);
                        }
                    }
                } else if (EPI == 3) {
                    float gl = 0.5f * v * (1.0f + erff(v * 0.70710678118f));
                    outh[(size_t)row * CD + col] = f2bf(gl);
                } else {
                    outf[(size_t)row * CD + col] = v + xaux[(size_t)row * CD + col];
                }
            }
        }
    }
}

extern "C" void kernel_launch(void* const* d_in, const int* in_sizes, int n_in,
                              void* d_out, int out_size, void* d_ws, size_t ws_size,
                              hipStream_t stream) {
    const float* x      = (const float*)d_in[0];
    const float* ln_g   = (const float*)d_in[1];
    const float* ln_b   = (const float*)d_in[2];
    const float* gate_w = (const float*)d_in[3];
    const float* gate_b = (const float*)d_in[4];
    const float* pw1    = (const float*)d_in[5];
    const float* pb1    = (const float*)d_in[6];
    const float* pw2    = (const float*)d_in[7];
    const float* pb2    = (const float*)d_in[8];
    const float* fw     = (const float*)d_in[9];
    const float* cw[3]  = {(const float*)d_in[11], (const float*)d_in[13], (const float*)d_in[15]};
    const float* cb[3]  = {(const float*)d_in[12], (const float*)d_in[14], (const float*)d_in[16]};

    char* ws = (char*)d_ws;
    unsigned short* gwt  = (unsigned short*)(ws + 0);           // 768*768*2
    unsigned short* p1t  = (unsigned short*)(ws + 1179648);
    unsigned short* p2t  = (unsigned short*)(ws + 2359296);
    unsigned short* xn   = (unsigned short*)(ws + 3538944);     // 25216*768*2
    unsigned short* feat = (unsigned short*)(ws + 42270720);    // 25216*768*2 (per-branch reuse)
    float*          fused= (float*)         (ws + 81002496);    // 25216*768*4
    unsigned short* fsb  = (unsigned short*)(ws + 158466048);   // 25216*768*2
    unsigned short* h1   = (unsigned short*)(ws + 197197824);   // 25216*768*2

    dim3 wg(2304, 3);
    wprep3_kernel<<<wg, 256, 0, stream>>>(gate_w, pw1, pw2, gwt, p1t, p2t);
    ln_relu_kernel<<<MROWS, 256, 0, stream>>>(x, ln_g, ln_b, xn);

    dim3 gg(6, 197);   // 768/128 cols x 25216/128 rows
    dwconv_kernel<1><<<591, 256, 0, stream>>>(xn, cw[0], cb[0], feat);
    gemm_kernel<0><<<gg, 256, 0, stream>>>(feat, gwt, gate_b, x, fused, nullptr, fw);
    dwconv_kernel<2><<<591, 256, 0, stream>>>(xn, cw[1], cb[1], feat);
    gemm_kernel<1><<<gg, 256, 0, stream>>>(feat, gwt, gate_b, x, fused, nullptr, fw);
    dwconv_kernel<3><<<591, 256, 0, stream>>>(xn, cw[2], cb[2], feat);
    gemm_kernel<2><<<gg, 256, 0, stream>>>(feat, gwt, gate_b, x, fused, fsb, fw);

    gemm_kernel<3><<<gg, 256, 0, stream>>>(fsb, p1t, pb1, nullptr, nullptr, h1, nullptr);
    gemm_kernel<4><<<gg, 256, 0, stream>>>(h1, p2t, pb2, x, (float*)d_out, nullptr, nullptr);
}

// Round 3
// 764.114 us; speedup vs baseline: 1.6482x; 1.2834x over previous
//
#include <hip/hip_runtime.h>
#include <math.h>

// MultiScaleTransformerGSM on MI355X (gfx950).
// LN+ReLU(+bf16 x copy) -> per branch: dwconv -> gate GEMM with PURE-WRITE
// bf16 epilogue (softmax weight folded in) -> proj1 GEMM whose A-staging
// GATHERS the shifted 3-branch fusion on the fly -> proj2 GEMM + residual.

#define MROWS 25216   // B*T*N = 8*16*197
#define CD    768
#define NTOK  197
#define TFR   16

typedef __attribute__((ext_vector_type(8))) short short8;
typedef __attribute__((ext_vector_type(4))) float floatx4;

__device__ __forceinline__ unsigned short f2bf(float f) {
    union { float f; unsigned u; } v; v.f = f;
    unsigned r = v.u + 0x7FFFu + ((v.u >> 16) & 1u);
    return (unsigned short)(r >> 16);
}
__device__ __forceinline__ float bf2f(unsigned short h) {
    union { unsigned u; float f; } v; v.u = ((unsigned)h) << 16;
    return v.f;
}

// ---------------- LayerNorm + ReLU -> bf16  (also emits bf16 copy of x) ----------------
__global__ __launch_bounds__(256)
void ln_relu_kernel(const float* __restrict__ x, const float* __restrict__ g,
                    const float* __restrict__ b, unsigned short* __restrict__ xn,
                    unsigned short* __restrict__ xb) {
    int row = blockIdx.x;
    int tid = threadIdx.x;
    const float* xr = x + (size_t)row * CD;
    float v0 = xr[tid], v1 = xr[tid + 256], v2 = xr[tid + 512];
    float s = v0 + v1 + v2;
    __shared__ float red[8];
#pragma unroll
    for (int off = 32; off; off >>= 1) s += __shfl_down(s, off, 64);
    int lane = tid & 63, w = tid >> 6;
    if (lane == 0) red[w] = s;
    __syncthreads();
    float mean = (red[0] + red[1] + red[2] + red[3]) * (1.0f / CD);
    float d0 = v0 - mean, d1 = v1 - mean, d2 = v2 - mean;
    float s2 = d0 * d0 + d1 * d1 + d2 * d2;
#pragma unroll
    for (int off = 32; off; off >>= 1) s2 += __shfl_down(s2, off, 64);
    if (lane == 0) red[4 + w] = s2;
    __syncthreads();
    float var = (red[4] + red[5] + red[6] + red[7]) * (1.0f / CD);
    float inv = rsqrtf(var + 1e-5f);
    unsigned short* xo = xn + (size_t)row * CD;
    unsigned short* xc = xb + (size_t)row * CD;
    float o0 = fmaxf(d0 * inv * g[tid]       + b[tid],       0.0f);
    float o1 = fmaxf(d1 * inv * g[tid + 256] + b[tid + 256], 0.0f);
    float o2 = fmaxf(d2 * inv * g[tid + 512] + b[tid + 512], 0.0f);
    xo[tid] = f2bf(o0); xo[tid + 256] = f2bf(o1); xo[tid + 512] = f2bf(o2);
    xc[tid] = f2bf(v0); xc[tid + 256] = f2bf(v1); xc[tid + 512] = f2bf(v2);
}

// ---------------- Depthwise conv over T, full-T register blocking ----------------
template <int D>
__global__ __launch_bounds__(256)
void dwconv_kernel(const unsigned short* __restrict__ xn, const float* __restrict__ cw,
                   const float* __restrict__ cb, unsigned short* __restrict__ feat) {
    constexpr int KK = 2 * D + 1;
    int gid = blockIdx.x * 256 + threadIdx.x;     // 8*197*96 = 151296 = 591*256
    int bn = gid / 96;
    int cg = gid - bn * 96;
    int c0 = cg * 8;
    int b = bn / NTOK;
    size_t base = ((size_t)b * TFR * NTOK + (bn - b * NTOK)) * CD + c0;
    const size_t tstride = (size_t)NTOK * CD;

    short8 u[TFR];
#pragma unroll
    for (int t = 0; t < TFR; ++t)
        u[t] = *(const short8*)(xn + base + (size_t)t * tstride);

    float wgt[8][KK], bb[8];
#pragma unroll
    for (int q = 0; q < 8; ++q) {
        bb[q] = cb[c0 + q];
#pragma unroll
        for (int j = 0; j < KK; ++j) wgt[q][j] = cw[(c0 + q) * KK + j];
    }

#pragma unroll
    for (int t = 0; t < TFR; ++t) {
        float acc[8];
#pragma unroll
        for (int q = 0; q < 8; ++q) acc[q] = bb[q];
#pragma unroll
        for (int j = 0; j < KK; ++j) {
            int tj = t + j - D;
            if (tj < 0 || tj >= TFR) continue;   // compile-time (t,j unrolled)
#pragma unroll
            for (int q = 0; q < 8; ++q)
                acc[q] += bf2f((unsigned short)u[tj][q]) * wgt[q][j];
        }
        short8 o;
#pragma unroll
        for (int q = 0; q < 8; ++q) o[q] = (short)f2bf(acc[q]);
        *(short8*)(feat + base + (size_t)t * tstride) = o;
    }
}

// ---------------- weight transpose+convert: wt[n][k] = bf16(w[k][n]) ----------------
__global__ __launch_bounds__(256)
void wprep3_kernel(const float* __restrict__ w0, const float* __restrict__ w1,
                   const float* __restrict__ w2, unsigned short* __restrict__ t0,
                   unsigned short* __restrict__ t1, unsigned short* __restrict__ t2) {
    const float* w = blockIdx.y == 0 ? w0 : blockIdx.y == 1 ? w1 : w2;
    unsigned short* wt = blockIdx.y == 0 ? t0 : blockIdx.y == 1 ? t1 : t2;
    int gid = blockIdx.x * 256 + threadIdx.x;
    int n = gid / CD, k = gid - n * CD;
    wt[gid] = f2bf(w[(size_t)k * CD + n]);
}

// ---------------- 128x128-tile bf16 MFMA GEMM ----------------
// EPI 0: gate  -> pure write bf16( wd * sigmoid(v) * xb )
// EPI 1: proj1 -> A-staging gathers shifted fusion of g1,g2,g3; gelu -> bf16
// EPI 2: proj2 -> v + x -> fp32 out
template <int EPI>
__global__ __launch_bounds__(256)
void gemm_kernel(const unsigned short* __restrict__ A,
                 const unsigned short* __restrict__ Bt,   // 768x768 bf16, N-major
                 const float* __restrict__ bias,
                 const unsigned short* __restrict__ xb,   // bf16 x (EPI0)
                 const float* __restrict__ xf,            // fp32 x (EPI2)
                 const unsigned short* __restrict__ g1,
                 const unsigned short* __restrict__ g2,
                 const unsigned short* __restrict__ g3,
                 float* __restrict__ outf,
                 unsigned short* __restrict__ outh,
                 const float* __restrict__ fw,
                 int widx) {
    __shared__ unsigned short As[128][40];
    __shared__ unsigned short Bs[128][40];
    int tid  = threadIdx.x;
    int n0   = blockIdx.x * 128;
    int m0   = blockIdx.y * 128;
    int wave = tid >> 6, lane = tid & 63;
    int wm   = (wave >> 1) * 64, wn = (wave & 1) * 64;
    int quad = lane >> 4, l16 = lane & 15;

    floatx4 acc[4][4];
#pragma unroll
    for (int i = 0; i < 4; ++i)
#pragma unroll
        for (int j = 0; j < 4; ++j) acc[i][j] = (floatx4){0.f, 0.f, 0.f, 0.f};

    int sr = tid >> 2;
    int sk = (tid & 3) * 8;

    for (int kt = 0; kt < CD; kt += 32) {
        __syncthreads();
#pragma unroll
        for (int h = 0; h < 2; ++h) {
            int row = sr + h * 64;
            if (EPI == 1) {
                // gather fused[m][kk] = sum_d shifted y_d (weights pre-folded)
                int m  = m0 + row;
                int t  = (m / NTOK) & 15;
                int kk = kt + sk;          // region uniform across the wave
                float vals[8] = {0.f,0.f,0.f,0.f,0.f,0.f,0.f,0.f};
                const unsigned short* ybs[3] = {g1, g2, g3};
#pragma unroll
                for (int d = 1; d <= 3; ++d) {
                    int src; bool ok;
                    if (kk < 256)      { src = m + d * NTOK; ok = (t + d) < TFR; }
                    else if (kk < 512) { src = m - d * NTOK; ok = (t - d) >= 0; }
                    else               { src = m;            ok = true; }
                    if (ok) {
                        short8 u = *(const short8*)(ybs[d - 1] + (size_t)src * CD + kk);
#pragma unroll
                        for (int q = 0; q < 8; ++q) vals[q] += bf2f((unsigned short)u[q]);
                    }
                }
                short8 o;
#pragma unroll
                for (int q = 0; q < 8; ++q) o[q] = (short)f2bf(vals[q]);
                *(short8*)(&As[row][sk]) = o;
            } else {
                *(short8*)(&As[row][sk]) = *(const short8*)(A + (size_t)(m0 + row) * CD + kt + sk);
            }
            *(short8*)(&Bs[row][sk]) = *(const short8*)(Bt + (size_t)(n0 + row) * CD + kt + sk);
        }
        __syncthreads();
        short8 af[4], bfr[4];
#pragma unroll
        for (int i = 0; i < 4; ++i) af[i]  = *(const short8*)(&As[wm + i * 16 + l16][quad * 8]);
#pragma unroll
        for (int j = 0; j < 4; ++j) bfr[j] = *(const short8*)(&Bs[wn + j * 16 + l16][quad * 8]);
#pragma unroll
        for (int i = 0; i < 4; ++i)
#pragma unroll
            for (int j = 0; j < 4; ++j)
                acc[i][j] = __builtin_amdgcn_mfma_f32_16x16x32_bf16(af[i], bfr[j], acc[i][j], 0, 0, 0);
    }

    float wd = 0.f;
    if (EPI == 0) {
        float f0 = fw[0], f1 = fw[1], f2 = fw[2];
        float mx = fmaxf(f0, fmaxf(f1, f2));
        float e0 = expf(f0 - mx), e1 = expf(f1 - mx), e2 = expf(f2 - mx);
        float inv = 1.f / (e0 + e1 + e2);
        wd = (widx == 0 ? e0 : widx == 1 ? e1 : e2) * inv;
    }

#pragma unroll
    for (int j = 0; j < 4; ++j) {
        int col = n0 + wn + j * 16 + l16;
        float bc = bias[col];
#pragma unroll
        for (int i = 0; i < 4; ++i) {
#pragma unroll
            for (int r = 0; r < 4; ++r) {
                int row = m0 + wm + i * 16 + quad * 4 + r;   // C/D: col=lane&15, row=quad*4+reg
                size_t idx = (size_t)row * CD + col;
                float v = acc[i][j][r] + bc;
                if (EPI == 0) {
                    float gte = 1.f / (1.f + expf(-v));
                    outh[idx] = f2bf(wd * gte * bf2f(xb[idx]));
                } else if (EPI == 1) {
                    float gl = 0.5f * v * (1.0f + erff(v * 0.70710678118f));
                    outh[idx] = f2bf(gl);
                } else {
                    outf[idx] = v + xf[idx];
                }
            }
        }
    }
}

extern "C" void kernel_launch(void* const* d_in, const int* in_sizes, int n_in,
                              void* d_out, int out_size, void* d_ws, size_t ws_size,
                              hipStream_t stream) {
    const float* x      = (const float*)d_in[0];
    const float* ln_g   = (const float*)d_in[1];
    const float* ln_b   = (const float*)d_in[2];
    const float* gate_w = (const float*)d_in[3];
    const float* gate_b = (const float*)d_in[4];
    const float* pw1    = (const float*)d_in[5];
    const float* pb1    = (const float*)d_in[6];
    const float* pw2    = (const float*)d_in[7];
    const float* pb2    = (const float*)d_in[8];
    const float* fw     = (const float*)d_in[9];
    const float* cw[3]  = {(const float*)d_in[11], (const float*)d_in[13], (const float*)d_in[15]};
    const float* cb[3]  = {(const float*)d_in[12], (const float*)d_in[14], (const float*)d_in[16]};

    char* ws = (char*)d_ws;
    const size_t SB = (size_t)MROWS * CD * 2;                   // 38,731,776
    unsigned short* gwt  = (unsigned short*)(ws + 0);           // 3 x 1,179,648 weights
    unsigned short* p1t  = (unsigned short*)(ws + 1179648);
    unsigned short* p2t  = (unsigned short*)(ws + 2359296);
    unsigned short* xn   = (unsigned short*)(ws + 3538944);
    unsigned short* xb   = (unsigned short*)(ws + 3538944 + SB);
    unsigned short* feat = (unsigned short*)(ws + 3538944 + 2 * SB);
    unsigned short* y1   = (unsigned short*)(ws + 3538944 + 3 * SB);
    unsigned short* y2   = (unsigned short*)(ws + 3538944 + 4 * SB);
    unsigned short* y3   = (unsigned short*)(ws + 3538944 + 5 * SB);
    unsigned short* h1   = y1;  // proj1 A-gather reads y1..y3; h1 overwrites... NO: reuse feat instead
    h1 = feat;                  // feat is dead after the last gate GEMM
    // total: 3,538,944 + 6*SB = 235,929,600 bytes (same as round-1 footprint)

    dim3 wg(2304, 3);
    wprep3_kernel<<<wg, 256, 0, stream>>>(gate_w, pw1, pw2, gwt, p1t, p2t);
    ln_relu_kernel<<<MROWS, 256, 0, stream>>>(x, ln_g, ln_b, xn, xb);

    dim3 gg(6, 197);
    dwconv_kernel<1><<<591, 256, 0, stream>>>(xn, cw[0], cb[0], feat);
    gemm_kernel<0><<<gg, 256, 0, stream>>>(feat, gwt, gate_b, xb, nullptr,
                                           nullptr, nullptr, nullptr, nullptr, y1, fw, 0);
    dwconv_kernel<2><<<591, 256, 0, stream>>>(xn, cw[1], cb[1], feat);
    gemm_kernel<0><<<gg, 256, 0, stream>>>(feat, gwt, gate_b, xb, nullptr,
                                           nullptr, nullptr, nullptr, nullptr, y2, fw, 1);
    dwconv_kernel<3><<<591, 256, 0, stream>>>(xn, cw[2], cb[2], feat);
    gemm_kernel<0><<<gg, 256, 0, stream>>>(feat, gwt, gate_b, xb, nullptr,
                                           nullptr, nullptr, nullptr, nullptr, y3, fw, 2);

    // proj1: A-staging gathers the shifted fusion of y1,y2,y3; h1 reuses feat
    gemm_kernel<1><<<gg, 256, 0, stream>>>(nullptr, p1t, pb1, nullptr, nullptr,
                                           y1, y2, y3, nullptr, h1, nullptr, 0);
    gemm_kernel<2><<<gg, 256, 0, stream>>>(h1, p2t, pb2, nullptr, x,
                                           nullptr, nullptr, nullptr, (float*)d_out, nullptr, nullptr, 0);
}

// Round 4
// 725.586 us; speedup vs baseline: 1.7358x; 1.0531x over previous
//
#include <hip/hip_runtime.h>
#include <math.h>

// MultiScaleTransformerGSM on MI355X (gfx950).
// LN+ReLU(+bf16 x copy) -> per branch: dwconv -> gate GEMM (global_load_lds
// staging, pure-write bf16 epilogue w/ folded softmax weight) -> proj1 GEMM
// whose A-staging gathers the shifted fusion -> proj2 GEMM + residual.

#define MROWS 25216   // B*T*N = 8*16*197
#define CD    768
#define NTOK  197
#define TFR   16

typedef __attribute__((ext_vector_type(8))) short short8;
typedef __attribute__((ext_vector_type(4))) float floatx4;
typedef unsigned int u32;

__device__ __forceinline__ unsigned short f2bf(float f) {
    union { float f; unsigned u; } v; v.f = f;
    unsigned r = v.u + 0x7FFFu + ((v.u >> 16) & 1u);
    return (unsigned short)(r >> 16);
}
__device__ __forceinline__ float bf2f(unsigned short h) {
    union { unsigned u; float f; } v; v.u = ((unsigned)h) << 16;
    return v.f;
}

// async global->LDS, 16B per lane; LDS dest = wave-uniform base + lane*16
__device__ __forceinline__ void gl2lds16(const void* g, void* l) {
    __builtin_amdgcn_global_load_lds(
        (__attribute__((address_space(1))) void*)(unsigned long long)g,
        (__attribute__((address_space(3))) void*)(u32)(unsigned long long)l,
        16, 0, 0);
}

// ---------------- LayerNorm + ReLU -> bf16 (also emits bf16 copy of x) ----------------
__global__ __launch_bounds__(256)
void ln_relu_kernel(const float* __restrict__ x, const float* __restrict__ g,
                    const float* __restrict__ b, unsigned short* __restrict__ xn,
                    unsigned short* __restrict__ xb) {
    int row = blockIdx.x;
    int tid = threadIdx.x;
    const float* xr = x + (size_t)row * CD;
    float v0 = xr[tid], v1 = xr[tid + 256], v2 = xr[tid + 512];
    float s = v0 + v1 + v2;
    __shared__ float red[8];
#pragma unroll
    for (int off = 32; off; off >>= 1) s += __shfl_down(s, off, 64);
    int lane = tid & 63, w = tid >> 6;
    if (lane == 0) red[w] = s;
    __syncthreads();
    float mean = (red[0] + red[1] + red[2] + red[3]) * (1.0f / CD);
    float d0 = v0 - mean, d1 = v1 - mean, d2 = v2 - mean;
    float s2 = d0 * d0 + d1 * d1 + d2 * d2;
#pragma unroll
    for (int off = 32; off; off >>= 1) s2 += __shfl_down(s2, off, 64);
    if (lane == 0) red[4 + w] = s2;
    __syncthreads();
    float var = (red[4] + red[5] + red[6] + red[7]) * (1.0f / CD);
    float inv = rsqrtf(var + 1e-5f);
    unsigned short* xo = xn + (size_t)row * CD;
    unsigned short* xc = xb + (size_t)row * CD;
    float o0 = fmaxf(d0 * inv * g[tid]       + b[tid],       0.0f);
    float o1 = fmaxf(d1 * inv * g[tid + 256] + b[tid + 256], 0.0f);
    float o2 = fmaxf(d2 * inv * g[tid + 512] + b[tid + 512], 0.0f);
    xo[tid] = f2bf(o0); xo[tid + 256] = f2bf(o1); xo[tid + 512] = f2bf(o2);
    xc[tid] = f2bf(v0); xc[tid + 256] = f2bf(v1); xc[tid + 512] = f2bf(v2);
}

// ---------------- Depthwise conv over T, full-T register blocking ----------------
template <int D>
__global__ __launch_bounds__(256)
void dwconv_kernel(const unsigned short* __restrict__ xn, const float* __restrict__ cw,
                   const float* __restrict__ cb, unsigned short* __restrict__ feat) {
    constexpr int KK = 2 * D + 1;
    int gid = blockIdx.x * 256 + threadIdx.x;     // 591*256 exact
    int bn = gid / 96;
    int cg = gid - bn * 96;
    int c0 = cg * 8;
    int b = bn / NTOK;
    size_t base = ((size_t)b * TFR * NTOK + (bn - b * NTOK)) * CD + c0;
    const size_t tstride = (size_t)NTOK * CD;

    short8 u[TFR];
#pragma unroll
    for (int t = 0; t < TFR; ++t)
        u[t] = *(const short8*)(xn + base + (size_t)t * tstride);

    float wgt[8][KK], bb[8];
#pragma unroll
    for (int q = 0; q < 8; ++q) {
        bb[q] = cb[c0 + q];
#pragma unroll
        for (int j = 0; j < KK; ++j) wgt[q][j] = cw[(c0 + q) * KK + j];
    }

#pragma unroll
    for (int t = 0; t < TFR; ++t) {
        float acc[8];
#pragma unroll
        for (int q = 0; q < 8; ++q) acc[q] = bb[q];
#pragma unroll
        for (int j = 0; j < KK; ++j) {
            int tj = t + j - D;
            if (tj < 0 || tj >= TFR) continue;   // compile-time (t,j unrolled)
#pragma unroll
            for (int q = 0; q < 8; ++q)
                acc[q] += bf2f((unsigned short)u[tj][q]) * wgt[q][j];
        }
        short8 o;
#pragma unroll
        for (int q = 0; q < 8; ++q) o[q] = (short)f2bf(acc[q]);
        *(short8*)(feat + base + (size_t)t * tstride) = o;
    }
}

// ---------------- weight transpose+convert: wt[n][k] = bf16(w[k][n]) ----------------
__global__ __launch_bounds__(256)
void wprep3_kernel(const float* __restrict__ w0, const float* __restrict__ w1,
                   const float* __restrict__ w2, unsigned short* __restrict__ t0,
                   unsigned short* __restrict__ t1, unsigned short* __restrict__ t2) {
    const float* w = blockIdx.y == 0 ? w0 : blockIdx.y == 1 ? w1 : w2;
    unsigned short* wt = blockIdx.y == 0 ? t0 : blockIdx.y == 1 ? t1 : t2;
    int gid = blockIdx.x * 256 + threadIdx.x;
    int n = gid / CD, k = gid - n * CD;
    wt[gid] = f2bf(w[(size_t)k * CD + n]);
}

// ---------------- 128x128-tile bf16 MFMA GEMM, global_load_lds staging ----------------
// EPI 0: gate  -> pure write bf16( wd * sigmoid(v) * xb )
// EPI 1: proj1 -> A-staging gathers shifted fusion of g1,g2,g3; gelu -> bf16
// EPI 2: proj2 -> v + x -> fp32 out
// LDS layout (unpadded, required by global_load_lds): chunk q (0..7) covers
// rows q*16..q*16+15; lane i of the issuing wave lands at q*1024 + i*16 bytes,
// i.e. row q*16+i/4, shorts (i%4)*8 — matches the global address mapping.
template <int EPI>
__global__ __launch_bounds__(256)
void gemm_kernel(const unsigned short* __restrict__ A,
                 const unsigned short* __restrict__ Bt,   // 768x768 bf16, N-major
                 const float* __restrict__ bias,
                 const unsigned short* __restrict__ xb,
                 const float* __restrict__ xf,
                 const unsigned short* __restrict__ g1,
                 const unsigned short* __restrict__ g2,
                 const unsigned short* __restrict__ g3,
                 float* __restrict__ outf,
                 unsigned short* __restrict__ outh,
                 const float* __restrict__ fw,
                 int widx) {
    __shared__ unsigned short As[128 * 32];
    __shared__ unsigned short Bs[128 * 32];
    int tid  = threadIdx.x;
    int m0   = blockIdx.x * 128;   // m fastest -> concurrent blocks share B n-tile
    int n0   = blockIdx.y * 128;
    int wave = tid >> 6, lane = tid & 63;
    int wm   = (wave >> 1) * 64, wn = (wave & 1) * 64;
    int quad = lane >> 4, l16 = lane & 15;
    int r4   = lane >> 2;          // 0..15: row within chunk
    int ck   = (lane & 3) * 8;     // k-chunk (shorts)

    floatx4 acc[4][4];
#pragma unroll
    for (int i = 0; i < 4; ++i)
#pragma unroll
        for (int j = 0; j < 4; ++j) acc[i][j] = (floatx4){0.f, 0.f, 0.f, 0.f};

    for (int kt = 0; kt < CD; kt += 32) {
        __syncthreads();
#pragma unroll
        for (int h = 0; h < 2; ++h) {
            int q   = wave + h * 4;          // chunk 0..7
            int row = q * 16 + r4;
            if (EPI == 1) {
                // gather fused[m][kk] = sum_d shifted y_d (softmax weights pre-folded)
                int m  = m0 + row;
                int t  = (m / NTOK) & 15;
                int kk = kt + ck;            // region const over the 8-short chunk
                float vals[8] = {0.f, 0.f, 0.f, 0.f, 0.f, 0.f, 0.f, 0.f};
                const unsigned short* ybs[3] = {g1, g2, g3};
#pragma unroll
                for (int d = 1; d <= 3; ++d) {
                    int src; bool ok;
                    if (kk < 256)      { src = m + d * NTOK; ok = (t + d) < TFR; }
                    else if (kk < 512) { src = m - d * NTOK; ok = (t - d) >= 0; }
                    else               { src = m;            ok = true; }
                    if (ok) {
                        short8 u = *(const short8*)(ybs[d - 1] + (size_t)src * CD + kk);
#pragma unroll
                        for (int e = 0; e < 8; ++e) vals[e] += bf2f((unsigned short)u[e]);
                    }
                }
                short8 o;
#pragma unroll
                for (int e = 0; e < 8; ++e) o[e] = (short)f2bf(vals[e]);
                *(short8*)(&As[q * 512 + lane * 8]) = o;   // same layout as gl2lds16
            } else {
                gl2lds16(A + (size_t)(m0 + row) * CD + kt + ck, &As[q * 512]);
            }
            gl2lds16(Bt + (size_t)(n0 + row) * CD + kt + ck, &Bs[q * 512]);
        }
        __syncthreads();
        short8 af[4], bfr[4];
#pragma unroll
        for (int i = 0; i < 4; ++i) af[i]  = *(const short8*)(&As[(wm + i * 16 + l16) * 32 + quad * 8]);
#pragma unroll
        for (int j = 0; j < 4; ++j) bfr[j] = *(const short8*)(&Bs[(wn + j * 16 + l16) * 32 + quad * 8]);
#pragma unroll
        for (int i = 0; i < 4; ++i)
#pragma unroll
            for (int j = 0; j < 4; ++j)
                acc[i][j] = __builtin_amdgcn_mfma_f32_16x16x32_bf16(af[i], bfr[j], acc[i][j], 0, 0, 0);
    }

    float wd = 0.f;
    if (EPI == 0) {
        float f0 = fw[0], f1 = fw[1], f2 = fw[2];
        float mx = fmaxf(f0, fmaxf(f1, f2));
        float e0 = expf(f0 - mx), e1 = expf(f1 - mx), e2 = expf(f2 - mx);
        float inv = 1.f / (e0 + e1 + e2);
        wd = (widx == 0 ? e0 : widx == 1 ? e1 : e2) * inv;
    }

#pragma unroll
    for (int j = 0; j < 4; ++j) {
        int col = n0 + wn + j * 16 + l16;
        float bc = bias[col];
#pragma unroll
        for (int i = 0; i < 4; ++i) {
#pragma unroll
            for (int r = 0; r < 4; ++r) {
                int row = m0 + wm + i * 16 + quad * 4 + r;   // C/D: col=lane&15, row=quad*4+reg
                size_t idx = (size_t)row * CD + col;
                float v = acc[i][j][r] + bc;
                if (EPI == 0) {
                    float gte = 1.f / (1.f + expf(-v));
                    outh[idx] = f2bf(wd * gte * bf2f(xb[idx]));
                } else if (EPI == 1) {
                    float gl = 0.5f * v * (1.0f + erff(v * 0.70710678118f));
                    outh[idx] = f2bf(gl);
                } else {
                    outf[idx] = v + xf[idx];
                }
            }
        }
    }
}

extern "C" void kernel_launch(void* const* d_in, const int* in_sizes, int n_in,
                              void* d_out, int out_size, void* d_ws, size_t ws_size,
                              hipStream_t stream) {
    const float* x      = (const float*)d_in[0];
    const float* ln_g   = (const float*)d_in[1];
    const float* ln_b   = (const float*)d_in[2];
    const float* gate_w = (const float*)d_in[3];
    const float* gate_b = (const float*)d_in[4];
    const float* pw1    = (const float*)d_in[5];
    const float* pb1    = (const float*)d_in[6];
    const float* pw2    = (const float*)d_in[7];
    const float* pb2    = (const float*)d_in[8];
    const float* fw     = (const float*)d_in[9];
    const float* cw[3]  = {(const float*)d_in[11], (const float*)d_in[13], (const float*)d_in[15]};
    const float* cb[3]  = {(const float*)d_in[12], (const float*)d_in[14], (const float*)d_in[16]};

    char* ws = (char*)d_ws;
    const size_t SB = (size_t)MROWS * CD * 2;                   // 38,731,776
    unsigned short* gwt  = (unsigned short*)(ws + 0);
    unsigned short* p1t  = (unsigned short*)(ws + 1179648);
    unsigned short* p2t  = (unsigned short*)(ws + 2359296);
    unsigned short* xn   = (unsigned short*)(ws + 3538944);
    unsigned short* xb   = (unsigned short*)(ws + 3538944 + SB);
    unsigned short* feat = (unsigned short*)(ws + 3538944 + 2 * SB);
    unsigned short* y1   = (unsigned short*)(ws + 3538944 + 3 * SB);
    unsigned short* y2   = (unsigned short*)(ws + 3538944 + 4 * SB);
    unsigned short* y3   = (unsigned short*)(ws + 3538944 + 5 * SB);
    unsigned short* h1   = feat;   // feat dead after last gate GEMM
    // total: 3,538,944 + 6*SB = 235,929,600 bytes

    dim3 wg(2304, 3);
    wprep3_kernel<<<wg, 256, 0, stream>>>(gate_w, pw1, pw2, gwt, p1t, p2t);
    ln_relu_kernel<<<MROWS, 256, 0, stream>>>(x, ln_g, ln_b, xn, xb);

    dim3 gg(197, 6);   // m-tiles fastest: concurrent blocks share one B n-tile
    dwconv_kernel<1><<<591, 256, 0, stream>>>(xn, cw[0], cb[0], feat);
    gemm_kernel<0><<<gg, 256, 0, stream>>>(feat, gwt, gate_b, xb, nullptr,
                                           nullptr, nullptr, nullptr, nullptr, y1, fw, 0);
    dwconv_kernel<2><<<591, 256, 0, stream>>>(xn, cw[1], cb[1], feat);
    gemm_kernel<0><<<gg, 256, 0, stream>>>(feat, gwt, gate_b, xb, nullptr,
                                           nullptr, nullptr, nullptr, nullptr, y2, fw, 1);
    dwconv_kernel<3><<<591, 256, 0, stream>>>(xn, cw[2], cb[2], feat);
    gemm_kernel<0><<<gg, 256, 0, stream>>>(feat, gwt, gate_b, xb, nullptr,
                                           nullptr, nullptr, nullptr, nullptr, y3, fw, 2);

    gemm_kernel<1><<<gg, 256, 0, stream>>>(nullptr, p1t, pb1, nullptr, nullptr,
                                           y1, y2, y3, nullptr, h1, nullptr, 0);
    gemm_kernel<2><<<gg, 256, 0, stream>>>(h1, p2t, pb2, nullptr, x,
                                           nullptr, nullptr, nullptr, (float*)d_out, nullptr, nullptr, 0);
}